// Round 4
// baseline (5029.558 us; speedup 1.0000x reference)
//
#include <hip/hip_runtime.h>

typedef _Float16 f16;
typedef _Float16 f16x8 __attribute__((ext_vector_type(8)));
typedef _Float16 f16x4 __attribute__((ext_vector_type(4)));
typedef float f32x4 __attribute__((ext_vector_type(4)));

// ---------------------------------------------------------------------------
// Dtype probe: scales true values lie in [0.01, 0.06]. Writes mode:
// 0=f16, 1=bf16, 2=f32. Graph-safe (no host sync).
// ---------------------------------------------------------------------------
__global__ void detect_kernel(const unsigned short* __restrict__ sc, int* __restrict__ mode)
{
    if (threadIdx.x != 0 || blockIdx.x != 0) return;
    bool ok16 = true, okbf = true;
    for (int i = 0; i < 64; i++) {
        const unsigned short b = sc[i];
        union { unsigned short u; f16 h; } ch; ch.u = b;
        const float fv = (float)ch.h;
        if (!(fv > 0.008f && fv < 0.062f)) ok16 = false;
        union { unsigned int u; float f; } cb; cb.u = ((unsigned int)b) << 16;
        if (!(cb.f > 0.008f && cb.f < 0.062f)) okbf = false;
    }
    *mode = ok16 ? 0 : (okbf ? 1 : 2);
}

__device__ __forceinline__ float load_half_like(const void* p, int i, int mode)
{
    if (mode == 0) return (float)((const f16*)p)[i];
    if (mode == 1) {
        union { unsigned int u; float f; } c;
        c.u = ((unsigned int)((const unsigned short*)p)[i]) << 16;
        return c.f;
    }
    return ((const float*)p)[i];
}

// ---------------------------------------------------------------------------
// Prep: dequant 4-bit -> f16 weights (code part exactly in f16, x f32 scale),
// lora_A -> f16, lora_B*0.125 -> f16, x -> f16, biases -> f32. Linear layouts.
// ---------------------------------------------------------------------------
__global__ void prep_kernel(const float* __restrict__ x, const int* __restrict__ qw,
                            const void* __restrict__ scales, const void* __restrict__ biases,
                            const float* __restrict__ lA, const float* __restrict__ lB,
                            const int* __restrict__ modep,
                            f16* __restrict__ Wdq, f16* __restrict__ A16,
                            f16* __restrict__ B16, f16* __restrict__ x16,
                            float* __restrict__ bias32)
{
    const int bid = blockIdx.x, tid = threadIdx.x;
    if (bid < 3840) {
        const int md = *modep;
        const int g = bid * 256 + tid;                 // group id; scale idx == g
        const float s = load_half_like(scales, g, md);
        const int4* qp = (const int4*)(qw + (size_t)g * 16);
        f16x8 w0, w1;
        #pragma unroll
        for (int v = 0; v < 4; v++) {
            const int4 q4 = qp[v];
            const int qs[4] = {q4.x, q4.y, q4.z, q4.w};
            #pragma unroll
            for (int j = 0; j < 4; j++) {
                f16 t = (f16)qs[j];
                t = t * (f16)(2.0f / 15.0f);           // f16 mul (matches ref)
                t = t - (f16)1.0f;                     // f16 sub
                const f16 w = (f16)((float)t * s);     // f32 scale mul, round once
                if (v < 2) w0[v * 4 + j] = w; else w1[(v - 2) * 4 + j] = w;
            }
        }
        *(f16x8*)(Wdq + (size_t)g * 16) = w0;
        *(f16x8*)(Wdq + (size_t)g * 16 + 8) = w1;
    } else if (bid < 4320) {
        const int i = (bid - 3840) * 1024 + tid * 4;
        const float4 a = *(const float4*)(lA + i);
        f16x4 o = {(f16)a.x, (f16)a.y, (f16)a.z, (f16)a.w};
        *(f16x4*)(A16 + i) = o;
    } else if (bid < 4800) {
        const int i = (bid - 4320) * 1024 + tid * 4;
        const float4 a = *(const float4*)(lB + i);
        f16x4 o = {(f16)(0.125f * a.x), (f16)(0.125f * a.y),
                   (f16)(0.125f * a.z), (f16)(0.125f * a.w)};
        *(f16x4*)(B16 + i) = o;
    } else if (bid < 12992) {
        const int i = (bid - 4800) * 1024 + tid * 4;
        const float4 a = *(const float4*)(x + i);
        f16x4 o = {(f16)a.x, (f16)a.y, (f16)a.z, (f16)a.w};
        *(f16x4*)(x16 + i) = o;
    } else {
        const int md = *modep;
        const int i = (bid - 12992) * 1024 + tid * 4;
        float4 o;
        o.x = load_half_like(biases, i, md);
        o.y = load_half_like(biases, i + 1, md);
        o.z = load_half_like(biases, i + 2, md);
        o.w = load_half_like(biases, i + 3, md);
        *(float4*)(bias32 + i) = o;
    }
}

// ---------------------------------------------------------------------------
// Fused QLoRA layer. 128x128 tile, 4 waves, LoRA stage-1 fused.
// ROUND 12: NO-LDS K-loop (register-streaming GEMM). Rounds 8-11 proved the
// time invariant (77-80us, MfmaUtil ~10.5) across scratch/DMA staging, XCD
// maps, 2/3 buffers, drain/counted vmcnt. The only constant was LDS staging
// itself: every iteration funnels the full A+B tile through the global->LDS
// path and a barrier gated on it (per-CU staged bytes identical in all four
// rounds). Fix: MFMA fragments for K-major operands are naturally per-lane
// 16B loads -- af[mi] = X[(row0+wy*64+mi*16+m15)*1024 + kt*32 + q2*8] -- so
// load A/B/loraA fragments straight to VGPRs. Intra-block 2x reuse is served
// by L1/L2 (W panel 2MB L2-resident per XCD under by%8 map; the 8 blocks
// sharing an X panel are co-resident). K-loop: 10 global_load_dwordx4 +
// 20 MFMAs, ZERO barriers / ds_read / DMA / asm waits. Depth-1 register
// ping-pong with statically named sets (runtime-indexed vectors -> scratch).
// LDS (36KB) remains for the epilogue only. Occupancy unchanged (8 waves/CU,
// VGPR ~190). MFMA order unchanged (32 asc. K-steps) -> bit-identical math.
// ---------------------------------------------------------------------------
__global__ __launch_bounds__(256, 2)
void layer_kernel(const f16* __restrict__ X16, const f16* __restrict__ W,
                  const f16* __restrict__ AL, const f16* __restrict__ BL,
                  const float* __restrict__ biasL, const float* __restrict__ resid,
                  float* __restrict__ out32, f16* __restrict__ out16, int do_relu)
{
    __shared__ __align__(16) f16 lds[18176];   // 36,352B: epilogue scratch only

    const int tid  = threadIdx.x;
    const int lane = tid & 63;
    const int wv   = tid >> 6;          // wave 0..3
    const int wy   = wv >> 1, wx = wv & 1;
    const int by   = blockIdx.x & 63;   // row block (64) -> XCD = blockIdx%8
    const int bx   = blockIdx.x >> 6;   // col block (8)
    const int row0 = by << 7;
    const int col0 = bx << 7;

    const int m15 = lane & 15;
    const int q2  = lane >> 4;          // 0..3
    const int q8  = q2 << 3;

    // per-lane fragment base pointers (K-major; 16B contiguous per lane)
    const f16* Ap = X16 + (size_t)(row0 + wy * 64 + m15) * 1024 + q8;
    const f16* Bp = W   + (size_t)(col0 + wx * 64 + m15) * 1024 + q8;
    const f16* Lp = AL  + (size_t)m15 * 1024 + q8;

    f32x4 acc[4][4] = {};
    f32x4 tacc[2][2] = {};

    f16x8 afA[4], bfA[4], lfA[2];       // register ping-pong, static names
    f16x8 afB[4], bfB[4], lfB[2];

    auto loadset = [&](int kt, f16x8 (&af)[4], f16x8 (&bf)[4], f16x8 (&lf)[2]) {
        const int kb = kt << 5;
        #pragma unroll
        for (int mi = 0; mi < 4; mi++)
            af[mi] = *(const f16x8*)(Ap + mi * 16384 + kb);
        #pragma unroll
        for (int ni = 0; ni < 4; ni++)
            bf[ni] = *(const f16x8*)(Bp + ni * 16384 + kb);
        #pragma unroll
        for (int pi = 0; pi < 2; pi++)
            lf[pi] = *(const f16x8*)(Lp + pi * 16384 + kb);
    };
    auto compute = [&](f16x8 (&af)[4], f16x8 (&bf)[4], f16x8 (&lf)[2]) {
        #pragma unroll
        for (int mi = 0; mi < 4; mi++)
            #pragma unroll
            for (int ni = 0; ni < 4; ni++)
                acc[mi][ni] = __builtin_amdgcn_mfma_f32_16x16x32_f16(af[mi], bf[ni], acc[mi][ni], 0, 0, 0);
        // lora stage-1: each wave covers its own 32 rows (m-frags 2wx, 2wx+1)
        #pragma unroll
        for (int mi = 0; mi < 2; mi++)
            #pragma unroll
            for (int pi = 0; pi < 2; pi++)
                tacc[mi][pi] = __builtin_amdgcn_mfma_f32_16x16x32_f16(af[2 * wx + mi], lf[pi], tacc[mi][pi], 0, 0, 0);
    };

    loadset(0, afA, bfA, lfA);
    #pragma unroll
    for (int k2 = 0; k2 < 16; k2++) {
        loadset(2 * k2 + 1, afB, bfB, lfB);   // prefetch next while computing
        compute(afA, bfA, lfA);
        if (k2 < 15) loadset(2 * k2 + 2, afA, bfA, lfA);
        compute(afB, bfB, lfB);
    }

    // ---- epilogue: lora stage-2 ----
    float* Tl = (float*)lds;   // [128][33] f32 padded (16.9KB)
    const int q4 = (lane >> 4) << 2;
    {
        #pragma unroll
        for (int mi = 0; mi < 2; mi++)
            #pragma unroll
            for (int pi = 0; pi < 2; pi++)
                #pragma unroll
                for (int r = 0; r < 4; r++)
                    Tl[(wy * 64 + wx * 32 + mi * 16 + q4 + r) * 33 + pi * 16 + m15] = tacc[mi][pi][r];
    }
    __syncthreads();

    f16x8 tf[4];    // T in A-fragment layout (k = lora dim, K=32 -> one k-step)
    #pragma unroll
    for (int mi = 0; mi < 4; mi++) {
        const float* tp = Tl + (wy * 64 + mi * 16 + m15) * 33 + q8;
        f16x8 v;
        #pragma unroll
        for (int j = 0; j < 8; j++) v[j] = (f16)tp[j];
        tf[mi] = v;
    }
    f16x8 bfr[4]; float bb[4];
    #pragma unroll
    for (int ni = 0; ni < 4; ni++) {
        const int colg = col0 + wx * 64 + ni * 16 + m15;
        bfr[ni] = *(const f16x8*)(BL + (size_t)colg * 32 + q8);  // pre-scaled 0.125
        bb[ni] = biasL[colg];
    }
    #pragma unroll
    for (int mi = 0; mi < 4; mi++)
        #pragma unroll
        for (int ni = 0; ni < 4; ni++) {
            #pragma unroll
            for (int r = 0; r < 4; r++)
                acc[mi][ni][r] += bb[ni];      // f32 bias add (ref promotes to f32)
            acc[mi][ni] = __builtin_amdgcn_mfma_f32_16x16x32_f16(tf[mi], bfr[ni], acc[mi][ni], 0, 0, 0);
        }

    // ---- epilogue: coalesced store through LDS ----
    __syncthreads();   // all waves done with Tl before LDS reuse
    if (out16) {
        // f16 path (j=0/1): relu, pack to LDS [128][136] (34.8KB), 16B/lane
        f16* ot = lds;
        #pragma unroll
        for (int mi = 0; mi < 4; mi++)
            #pragma unroll
            for (int ni = 0; ni < 4; ni++)
                #pragma unroll
                for (int r = 0; r < 4; r++) {
                    float v = acc[mi][ni][r];
                    if (do_relu) v = fmaxf(v, 0.0f);
                    ot[(wy * 64 + mi * 16 + q4 + r) * 136 + wx * 64 + ni * 16 + m15] = (f16)v;
                }
        __syncthreads();
        const int rr = tid >> 4;            // 0..15
        const int cc = (tid & 15) << 3;     // 16B chunks
        #pragma unroll
        for (int it = 0; it < 8; it++) {
            const int r = it * 16 + rr;
            const f16x8 v = *(const f16x8*)(ot + r * 136 + cc);
            *(f16x8*)(out16 + (size_t)(row0 + r) * 1024 + col0 + cc) = v;
        }
    } else {
        // f32 path (j=2): two 64-row halves through LDS [64][140] (35.8KB),
        // coalesced resid read + coalesced f32 store.
        float* otf = (float*)lds;
        const int rr = tid >> 5;            // 0..7
        const int cc = (tid & 31) << 2;     // 16B chunks (f32)
        #pragma unroll
        for (int half = 0; half < 2; half++) {
            if (wy == half) {
                #pragma unroll
                for (int mi = 0; mi < 4; mi++)
                    #pragma unroll
                    for (int ni = 0; ni < 4; ni++)
                        #pragma unroll
                        for (int r = 0; r < 4; r++)
                            otf[(mi * 16 + q4 + r) * 140 + wx * 64 + ni * 16 + m15] = acc[mi][ni][r];
            }
            __syncthreads();
            #pragma unroll
            for (int it = 0; it < 8; it++) {
                const int r = it * 8 + rr;
                f32x4 v = *(const f32x4*)(otf + r * 140 + cc);
                const size_t gidx = (size_t)(row0 + half * 64 + r) * 1024 + col0 + cc;
                const f32x4 rs = *(const f32x4*)(resid + gidx);
                v += rs;
                *(f32x4*)(out32 + gidx) = v;
            }
            if (half == 0) __syncthreads();
        }
    }
}

// ---------------------------------------------------------------------------
// LayerNorm over rows of h (f32, in place) + f16 copy for next GEMM input.
// ---------------------------------------------------------------------------
__global__ void ln_kernel(float* __restrict__ h, f16* __restrict__ h16,
                          const float* __restrict__ g, const float* __restrict__ b)
{
    const int row = blockIdx.x, tid = threadIdx.x;
    float* hp = h + (size_t)row * 1024;
    const int c = tid * 4;
    const float4 v = *(const float4*)(hp + c);
    float s = v.x + v.y + v.z + v.w;
    #pragma unroll
    for (int off = 32; off > 0; off >>= 1) s += __shfl_down(s, off);
    __shared__ float r1[4], r2[4];
    const int wv = tid >> 6, lane = tid & 63;
    if (lane == 0) r1[wv] = s;
    __syncthreads();
    const float mu = (r1[0] + r1[1] + r1[2] + r1[3]) * (1.0f / 1024.0f);
    const float dx = v.x - mu, dy = v.y - mu, dz = v.z - mu, dw = v.w - mu;
    float s2 = dx * dx + dy * dy + dz * dz + dw * dw;
    #pragma unroll
    for (int off = 32; off > 0; off >>= 1) s2 += __shfl_down(s2, off);
    if (lane == 0) r2[wv] = s2;
    __syncthreads();
    const float var = (r2[0] + r2[1] + r2[2] + r2[3]) * (1.0f / 1024.0f);
    const float rs = 1.0f / sqrtf(var + 1e-5f);
    float4 o;
    o.x = dx * rs * g[c]     + b[c];
    o.y = dy * rs * g[c + 1] + b[c + 1];
    o.z = dz * rs * g[c + 2] + b[c + 2];
    o.w = dw * rs * g[c + 3] + b[c + 3];
    *(float4*)(hp + c) = o;
    f16x4 o16 = {(f16)o.x, (f16)o.y, (f16)o.z, (f16)o.w};
    *(f16x4*)(h16 + (size_t)row * 1024 + c) = o16;
}

// ---------------------------------------------------------------------------
// ws layout (~64 MB): mode@0 | bias32@64 | Wdq@65536 | A16 | B16 | fA | fB
// f32 residual carrier lives in d_out (overwritten fully every call).
// ---------------------------------------------------------------------------
extern "C" void kernel_launch(void* const* d_in, const int* in_sizes, int n_in,
                              void* d_out, int out_size, void* d_ws, size_t ws_size,
                              hipStream_t stream)
{
    const float* x      = (const float*)d_in[0];
    const int*   qw     = (const int*)d_in[1];
    const void*  scales = d_in[2];
    const void*  biases = d_in[3];
    const float* lA     = (const float*)d_in[4];
    const float* lB     = (const float*)d_in[5];
    const float* lng    = (const float*)d_in[6];
    const float* lnb    = (const float*)d_in[7];
    float* out = (float*)d_out;

    char* ws = (char*)d_ws;
    int*   mode   = (int*)(ws);
    float* bias32 = (float*)(ws + 64);
    f16* Wdq = (f16*)(ws + 65536u);
    f16* A16 = (f16*)(ws + 31522816u);
    f16* B16 = (f16*)(ws + 32505856u);
    f16* fA  = (f16*)(ws + 33488896u);
    f16* fB  = (f16*)(ws + 50266112u);
    float* h32 = out;   // residual carrier in d_out

    detect_kernel<<<1, 64, 0, stream>>>((const unsigned short*)scales, mode);
    prep_kernel<<<13007, 256, 0, stream>>>(x, qw, scales, biases, lA, lB, mode,
                                           Wdq, A16, B16, fA, bias32);

    int li = 0;
    for (int blk = 0; blk < 6; blk++) {
        const float* resid = (blk == 0) ? x : h32;
        for (int j = 0; j < 3; j++, li++) {
            const int wl = li < 15 ? li : 14;      // JAX clamps q_w[15..17] -> 14
            const f16* in16 = (j == 1) ? fB : fA;
            f16* o16 = (j == 0) ? fB : (j == 1 ? fA : (f16*)nullptr);
            float* o32 = nullptr;
            const float* rz = nullptr;
            if (j == 2) { o32 = h32; rz = resid; }
            layer_kernel<<<512, 256, 0, stream>>>(in16,
                Wdq + (size_t)wl * 1048576,
                A16 + (size_t)wl * 32768,
                B16 + (size_t)wl * 32768,
                bias32 + (size_t)wl * 1024,
                rz, o32, o16, j < 2 ? 1 : 0);
        }
        if (blk < 5)
            ln_kernel<<<8192, 256, 0, stream>>>(h32, fA, lng + blk * 1024, lnb + blk * 1024);
    }
}

// Round 5
// 1936.536 us; speedup vs baseline: 2.5972x; 2.5972x over previous
//
#include <hip/hip_runtime.h>

typedef _Float16 f16;
typedef _Float16 f16x8 __attribute__((ext_vector_type(8)));
typedef _Float16 f16x4 __attribute__((ext_vector_type(4)));
typedef float f32x4 __attribute__((ext_vector_type(4)));

// ---------------------------------------------------------------------------
// Dtype probe: scales true values lie in [0.01, 0.06]. Writes mode:
// 0=f16, 1=bf16, 2=f32. Graph-safe (no host sync).
// ---------------------------------------------------------------------------
__global__ void detect_kernel(const unsigned short* __restrict__ sc, int* __restrict__ mode)
{
    if (threadIdx.x != 0 || blockIdx.x != 0) return;
    bool ok16 = true, okbf = true;
    for (int i = 0; i < 64; i++) {
        const unsigned short b = sc[i];
        union { unsigned short u; f16 h; } ch; ch.u = b;
        const float fv = (float)ch.h;
        if (!(fv > 0.008f && fv < 0.062f)) ok16 = false;
        union { unsigned int u; float f; } cb; cb.u = ((unsigned int)b) << 16;
        if (!(cb.f > 0.008f && cb.f < 0.062f)) okbf = false;
    }
    *mode = ok16 ? 0 : (okbf ? 1 : 2);
}

__device__ __forceinline__ float load_half_like(const void* p, int i, int mode)
{
    if (mode == 0) return (float)((const f16*)p)[i];
    if (mode == 1) {
        union { unsigned int u; float f; } c;
        c.u = ((unsigned int)((const unsigned short*)p)[i]) << 16;
        return c.f;
    }
    return ((const float*)p)[i];
}

// ---------------------------------------------------------------------------
// Prep: dequant 4-bit -> f16 weights (code part exactly in f16, x f32 scale),
// lora_A -> f16, lora_B*0.125 -> f16, x -> f16, biases -> f32. Linear layouts.
// ---------------------------------------------------------------------------
__global__ void prep_kernel(const float* __restrict__ x, const int* __restrict__ qw,
                            const void* __restrict__ scales, const void* __restrict__ biases,
                            const float* __restrict__ lA, const float* __restrict__ lB,
                            const int* __restrict__ modep,
                            f16* __restrict__ Wdq, f16* __restrict__ A16,
                            f16* __restrict__ B16, f16* __restrict__ x16,
                            float* __restrict__ bias32)
{
    const int bid = blockIdx.x, tid = threadIdx.x;
    if (bid < 3840) {
        const int md = *modep;
        const int g = bid * 256 + tid;                 // group id; scale idx == g
        const float s = load_half_like(scales, g, md);
        const int4* qp = (const int4*)(qw + (size_t)g * 16);
        f16x8 w0, w1;
        #pragma unroll
        for (int v = 0; v < 4; v++) {
            const int4 q4 = qp[v];
            const int qs[4] = {q4.x, q4.y, q4.z, q4.w};
            #pragma unroll
            for (int j = 0; j < 4; j++) {
                f16 t = (f16)qs[j];
                t = t * (f16)(2.0f / 15.0f);           // f16 mul (matches ref)
                t = t - (f16)1.0f;                     // f16 sub
                const f16 w = (f16)((float)t * s);     // f32 scale mul, round once
                if (v < 2) w0[v * 4 + j] = w; else w1[(v - 2) * 4 + j] = w;
            }
        }
        *(f16x8*)(Wdq + (size_t)g * 16) = w0;
        *(f16x8*)(Wdq + (size_t)g * 16 + 8) = w1;
    } else if (bid < 4320) {
        const int i = (bid - 3840) * 1024 + tid * 4;
        const float4 a = *(const float4*)(lA + i);
        f16x4 o = {(f16)a.x, (f16)a.y, (f16)a.z, (f16)a.w};
        *(f16x4*)(A16 + i) = o;
    } else if (bid < 4800) {
        const int i = (bid - 4320) * 1024 + tid * 4;
        const float4 a = *(const float4*)(lB + i);
        f16x4 o = {(f16)(0.125f * a.x), (f16)(0.125f * a.y),
                   (f16)(0.125f * a.z), (f16)(0.125f * a.w)};
        *(f16x4*)(B16 + i) = o;
    } else if (bid < 12992) {
        const int i = (bid - 4800) * 1024 + tid * 4;
        const float4 a = *(const float4*)(x + i);
        f16x4 o = {(f16)a.x, (f16)a.y, (f16)a.z, (f16)a.w};
        *(f16x4*)(x16 + i) = o;
    } else {
        const int md = *modep;
        const int i = (bid - 12992) * 1024 + tid * 4;
        float4 o;
        o.x = load_half_like(biases, i, md);
        o.y = load_half_like(biases, i + 1, md);
        o.z = load_half_like(biases, i + 2, md);
        o.w = load_half_like(biases, i + 3, md);
        *(float4*)(bias32 + i) = o;
    }
}

// global -> LDS direct DMA, 16B per lane (dest: wave-uniform base + lane*16B)
__device__ __forceinline__ void gl_lds16(const f16* g, f16* l)
{
    __builtin_amdgcn_global_load_lds(
        (const __attribute__((address_space(1))) void*)g,
        (__attribute__((address_space(3))) void*)l, 16, 0, 0);
}

// ---------------------------------------------------------------------------
// Fused QLoRA layer. ROUND 13: occupancy + phase-stagger.
// Evidence: r8-r11 all take a FIXED ~187k cycles (77-80us) regardless of
// iter count (16 vs 32), traffic (106-314MB), wait discipline (drain vs
// counted distance-2), LDS conflicts (196k vs 2.3M). Staging delivery is
// pinned at 6.2 B/cyc/CU vs m97's 22 B/cyc/CU with the SAME instruction +
// scatter pattern. Remaining delta to m97: occupancy (2 vs 3+ blocks/CU)
// and block queue (our 512 blocks = exactly 2/CU, all launched in lockstep
// -> co-resident blocks hit barrier drains simultaneously -> zero overlap,
// half the outstanding-request concurrency). Changes:
//   - 64x128 tile (M=64, N=128), BK=32 -> grid 1024 = 4 blocks/CU,
//     4 waves/SIMD. LDS: 2 x 14KB staging + 36KB epilogue max -> 4/CU.
//   - entry s_sleep stagger by co-residency slot (bid>>8)&3: 0/2k/4k/6k
//     cyc, breaking the lockstep so one block's compute covers another's
//     drain (m114 cross-block overlap mechanism).
// Structure otherwise r9-identical (2-phase barrier, source-side swizzle,
// DMA staging, ascending-K MFMA order -> bit-identical math).
// ---------------------------------------------------------------------------
__global__ __launch_bounds__(256, 4)
void layer_kernel(const f16* __restrict__ X16, const f16* __restrict__ W,
                  const f16* __restrict__ AL, const f16* __restrict__ BL,
                  const float* __restrict__ biasL, const float* __restrict__ resid,
                  float* __restrict__ out32, f16* __restrict__ out16, int do_relu)
{
    __shared__ __align__(16) f16 lds[17920];   // 35,840B: max(2x14KB stage, epi)

    const int tid  = threadIdx.x;
    const int lane = tid & 63;
    const int wv   = tid >> 6;          // wave 0..3
    const int wy   = wv >> 1, wx = wv & 1;
    const int bid  = blockIdx.x;
    const int by   = bid & 127;         // row block (128) -> XCD = bid%8
    const int bx   = bid >> 7;          // col block (8)
    const int row0 = by << 6;           // 64 rows
    const int col0 = bx << 7;           // 128 cols

    // phase stagger: co-resident slot (4 blocks/CU; pairs b, b+256, ...)
    {
        const int slot = (bid >> 8) & 3;
        for (int i = 0; i < slot; i++) __builtin_amdgcn_s_sleep(32);  // ~2k cyc
    }

    // staging: per DMA instr = 16 rows x 64B (4 chunks of 16B). LDS linear;
    // swizzle on GLOBAL source chunk: fetch chunk (lane&3)^(row&3).
    const int lr4 = lane >> 2;                          // row within 16-row DMA
    const int csw = (((lane & 3) ^ (lr4 & 3)) << 3);    // swizzled col (elems)

    // fragment reads: row r wants G-chunk q2 -> phys chunk q2^(r&3)
    const int m15 = lane & 15;
    const int q2  = lane >> 4;                          // 0..3
    const int po  = ((q2 ^ (m15 & 3)) << 3);            // phys col (elems)
    const int q8  = q2 << 3;

    f32x4 acc[2][4] = {};
    f32x4 tacc[2] = {};

    // buffer layout (f16 elems): sA[64][32] @0 | sB[128][32] @2048 | sL[32][32] @6144
    auto stage = [&](int kt, int bsel) {
        f16* buf = lds + bsel * 7168;
        const int kb = (kt << 5) + csw;
        gl_lds16(X16 + (size_t)(row0 + wv * 16 + lr4) * 1024 + kb,
                 buf + (wv * 16) * 32);
        #pragma unroll
        for (int i = 0; i < 2; i++)
            gl_lds16(W + (size_t)(col0 + wv * 32 + i * 16 + lr4) * 1024 + kb,
                     buf + 2048 + (wv * 32 + i * 16) * 32);
        if (wv < 2)
            gl_lds16(AL + (size_t)(wv * 16 + lr4) * 1024 + kb,
                     buf + 6144 + (wv * 16) * 32);
    };

    stage(0, 0);                         // prologue: tile 0 in flight

    for (int kt = 0; kt < 32; kt++) {
        __syncthreads();                 // drains vmcnt(0): buf[kt&1] staged
        const f16* cur = lds + (kt & 1) * 7168;
        const f16* sA = cur;
        const f16* sB = cur + 2048;
        const f16* sL = cur + 6144;

        if (kt < 31) stage(kt + 1, (kt + 1) & 1);

        f16x8 af[2], bf[4], lf[2];
        #pragma unroll
        for (int mi = 0; mi < 2; mi++)
            af[mi] = *(const f16x8*)(sA + (wy * 32 + mi * 16 + m15) * 32 + po);
        #pragma unroll
        for (int ni = 0; ni < 4; ni++)
            bf[ni] = *(const f16x8*)(sB + (wx * 64 + ni * 16 + m15) * 32 + po);
        #pragma unroll
        for (int pi = 0; pi < 2; pi++)
            lf[pi] = *(const f16x8*)(sL + (pi * 16 + m15) * 32 + po);

        #pragma unroll
        for (int mi = 0; mi < 2; mi++)
            #pragma unroll
            for (int ni = 0; ni < 4; ni++)
                acc[mi][ni] = __builtin_amdgcn_mfma_f32_16x16x32_f16(af[mi], bf[ni], acc[mi][ni], 0, 0, 0);
        // lora stage-1: wave (wy,wx) owns rows wv*16..wv*16+15 == af[wx] rows
        #pragma unroll
        for (int pi = 0; pi < 2; pi++)
            tacc[pi] = __builtin_amdgcn_mfma_f32_16x16x32_f16(af[wx], lf[pi], tacc[pi], 0, 0, 0);
    }

    // ---- epilogue: lora stage-2 ----
    __syncthreads();
    float* Tl = (float*)lds;   // [64][33] f32 (8.4KB)
    const int q4 = q2 << 2;
    {
        #pragma unroll
        for (int pi = 0; pi < 2; pi++)
            #pragma unroll
            for (int r = 0; r < 4; r++)
                Tl[(wv * 16 + q4 + r) * 33 + pi * 16 + m15] = tacc[pi][r];
    }
    __syncthreads();

    f16x8 tf[2];    // T in A-fragment layout (k = lora dim, K=32 -> one k-step)
    #pragma unroll
    for (int mi = 0; mi < 2; mi++) {
        const float* tp = Tl + (wy * 32 + mi * 16 + m15) * 33 + q8;
        f16x8 v;
        #pragma unroll
        for (int j = 0; j < 8; j++) v[j] = (f16)tp[j];
        tf[mi] = v;
    }
    f16x8 bfr[4]; float bb[4];
    #pragma unroll
    for (int ni = 0; ni < 4; ni++) {
        const int colg = col0 + wx * 64 + ni * 16 + m15;
        bfr[ni] = *(const f16x8*)(BL + (size_t)colg * 32 + q8);  // pre-scaled 0.125
        bb[ni] = biasL[colg];
    }
    #pragma unroll
    for (int mi = 0; mi < 2; mi++)
        #pragma unroll
        for (int ni = 0; ni < 4; ni++) {
            #pragma unroll
            for (int r = 0; r < 4; r++)
                acc[mi][ni][r] += bb[ni];      // f32 bias add (ref promotes to f32)
            acc[mi][ni] = __builtin_amdgcn_mfma_f32_16x16x32_f16(tf[mi], bfr[ni], acc[mi][ni], 0, 0, 0);
        }

    // ---- epilogue: coalesced store through LDS ----
    __syncthreads();   // all waves done with Tl before LDS reuse
    if (out16) {
        // f16 path (j=0/1): relu, pack to LDS [64][136] (17.4KB), 16B/lane
        f16* ot = lds;
        #pragma unroll
        for (int mi = 0; mi < 2; mi++)
            #pragma unroll
            for (int ni = 0; ni < 4; ni++)
                #pragma unroll
                for (int r = 0; r < 4; r++) {
                    float v = acc[mi][ni][r];
                    if (do_relu) v = fmaxf(v, 0.0f);
                    ot[(wy * 32 + mi * 16 + q4 + r) * 136 + wx * 64 + ni * 16 + m15] = (f16)v;
                }
        __syncthreads();
        const int rr = tid >> 4;            // 0..15
        const int cc = (tid & 15) << 3;     // 16B chunks
        #pragma unroll
        for (int it = 0; it < 4; it++) {
            const int r = it * 16 + rr;
            const f16x8 v = *(const f16x8*)(ot + r * 136 + cc);
            *(f16x8*)(out16 + (size_t)(row0 + r) * 1024 + col0 + cc) = v;
        }
    } else {
        // f32 path (j=2): LDS [64][140] f32 (35.8KB), coalesced resid+store.
        float* otf = (float*)lds;
        #pragma unroll
        for (int mi = 0; mi < 2; mi++)
            #pragma unroll
            for (int ni = 0; ni < 4; ni++)
                #pragma unroll
                for (int r = 0; r < 4; r++)
                    otf[(wy * 32 + mi * 16 + q4 + r) * 140 + wx * 64 + ni * 16 + m15] = acc[mi][ni][r];
        __syncthreads();
        const int rr = tid >> 5;            // 0..7
        const int cc = (tid & 31) << 2;     // 16B chunks (f32)
        #pragma unroll
        for (int it = 0; it < 8; it++) {
            const int r = it * 8 + rr;
            f32x4 v = *(const f32x4*)(otf + r * 140 + cc);
            const size_t gidx = (size_t)(row0 + r) * 1024 + col0 + cc;
            const f32x4 rs = *(const f32x4*)(resid + gidx);
            v += rs;
            *(f32x4*)(out32 + gidx) = v;
        }
    }
}

// ---------------------------------------------------------------------------
// LayerNorm over rows of h (f32, in place) + f16 copy for next GEMM input.
// ---------------------------------------------------------------------------
__global__ void ln_kernel(float* __restrict__ h, f16* __restrict__ h16,
                          const float* __restrict__ g, const float* __restrict__ b)
{
    const int row = blockIdx.x, tid = threadIdx.x;
    float* hp = h + (size_t)row * 1024;
    const int c = tid * 4;
    const float4 v = *(const float4*)(hp + c);
    float s = v.x + v.y + v.z + v.w;
    #pragma unroll
    for (int off = 32; off > 0; off >>= 1) s += __shfl_down(s, off);
    __shared__ float r1[4], r2[4];
    const int wv = tid >> 6, lane = tid & 63;
    if (lane == 0) r1[wv] = s;
    __syncthreads();
    const float mu = (r1[0] + r1[1] + r1[2] + r1[3]) * (1.0f / 1024.0f);
    const float dx = v.x - mu, dy = v.y - mu, dz = v.z - mu, dw = v.w - mu;
    float s2 = dx * dx + dy * dy + dz * dz + dw * dw;
    #pragma unroll
    for (int off = 32; off > 0; off >>= 1) s2 += __shfl_down(s2, off);
    if (lane == 0) r2[wv] = s2;
    __syncthreads();
    const float var = (r2[0] + r2[1] + r2[2] + r2[3]) * (1.0f / 1024.0f);
    const float rs = 1.0f / sqrtf(var + 1e-5f);
    float4 o;
    o.x = dx * rs * g[c]     + b[c];
    o.y = dy * rs * g[c + 1] + b[c + 1];
    o.z = dz * rs * g[c + 2] + b[c + 2];
    o.w = dw * rs * g[c + 3] + b[c + 3];
    *(float4*)(hp + c) = o;
    f16x4 o16 = {(f16)o.x, (f16)o.y, (f16)o.z, (f16)o.w};
    *(f16x4*)(h16 + (size_t)row * 1024 + c) = o16;
}

// ---------------------------------------------------------------------------
// ws layout (~64 MB): mode@0 | bias32@64 | Wdq@65536 | A16 | B16 | fA | fB
// f32 residual carrier lives in d_out (overwritten fully every call).
// ---------------------------------------------------------------------------
extern "C" void kernel_launch(void* const* d_in, const int* in_sizes, int n_in,
                              void* d_out, int out_size, void* d_ws, size_t ws_size,
                              hipStream_t stream)
{
    const float* x      = (const float*)d_in[0];
    const int*   qw     = (const int*)d_in[1];
    const void*  scales = d_in[2];
    const void*  biases = d_in[3];
    const float* lA     = (const float*)d_in[4];
    const float* lB     = (const float*)d_in[5];
    const float* lng    = (const float*)d_in[6];
    const float* lnb    = (const float*)d_in[7];
    float* out = (float*)d_out;

    char* ws = (char*)d_ws;
    int*   mode   = (int*)(ws);
    float* bias32 = (float*)(ws + 64);
    f16* Wdq = (f16*)(ws + 65536u);
    f16* A16 = (f16*)(ws + 31522816u);
    f16* B16 = (f16*)(ws + 32505856u);
    f16* fA  = (f16*)(ws + 33488896u);
    f16* fB  = (f16*)(ws + 50266112u);
    float* h32 = out;   // residual carrier in d_out

    detect_kernel<<<1, 64, 0, stream>>>((const unsigned short*)scales, mode);
    prep_kernel<<<13007, 256, 0, stream>>>(x, qw, scales, biases, lA, lB, mode,
                                           Wdq, A16, B16, fA, bias32);

    int li = 0;
    for (int blk = 0; blk < 6; blk++) {
        const float* resid = (blk == 0) ? x : h32;
        for (int j = 0; j < 3; j++, li++) {
            const int wl = li < 15 ? li : 14;      // JAX clamps q_w[15..17] -> 14
            const f16* in16 = (j == 1) ? fB : fA;
            f16* o16 = (j == 0) ? fB : (j == 1 ? fA : (f16*)nullptr);
            float* o32 = nullptr;
            const float* rz = nullptr;
            if (j == 2) { o32 = h32; rz = resid; }
            layer_kernel<<<1024, 256, 0, stream>>>(in16,
                Wdq + (size_t)wl * 1048576,
                A16 + (size_t)wl * 32768,
                B16 + (size_t)wl * 32768,
                bias32 + (size_t)wl * 1024,
                rz, o32, o16, j < 2 ? 1 : 0);
        }
        if (blk < 5)
            ln_kernel<<<8192, 256, 0, stream>>>(h32, fA, lng + blk * 1024, lnb + blk * 1024);
    }
}

// Round 6
// 1448.738 us; speedup vs baseline: 3.4717x; 1.3367x over previous
//
#include <hip/hip_runtime.h>

typedef _Float16 f16;
typedef _Float16 f16x8 __attribute__((ext_vector_type(8)));
typedef _Float16 f16x4 __attribute__((ext_vector_type(4)));
typedef float f32x4 __attribute__((ext_vector_type(4)));

// ---------------------------------------------------------------------------
// Dtype probe: scales true values lie in [0.01, 0.06]. Writes mode:
// 0=f16, 1=bf16, 2=f32. Graph-safe (no host sync).
// ---------------------------------------------------------------------------
__global__ void detect_kernel(const unsigned short* __restrict__ sc, int* __restrict__ mode)
{
    if (threadIdx.x != 0 || blockIdx.x != 0) return;
    bool ok16 = true, okbf = true;
    for (int i = 0; i < 64; i++) {
        const unsigned short b = sc[i];
        union { unsigned short u; f16 h; } ch; ch.u = b;
        const float fv = (float)ch.h;
        if (!(fv > 0.008f && fv < 0.062f)) ok16 = false;
        union { unsigned int u; float f; } cb; cb.u = ((unsigned int)b) << 16;
        if (!(cb.f > 0.008f && cb.f < 0.062f)) okbf = false;
    }
    *mode = ok16 ? 0 : (okbf ? 1 : 2);
}

__device__ __forceinline__ float load_half_like(const void* p, int i, int mode)
{
    if (mode == 0) return (float)((const f16*)p)[i];
    if (mode == 1) {
        union { unsigned int u; float f; } c;
        c.u = ((unsigned int)((const unsigned short*)p)[i]) << 16;
        return c.f;
    }
    return ((const float*)p)[i];
}

// ---------------------------------------------------------------------------
// Prep: dequant 4-bit -> f16 weights (code part exactly in f16, x f32 scale),
// lora_A -> f16, lora_B*0.125 -> f16, x -> f16, biases -> f32. Linear layouts.
// ---------------------------------------------------------------------------
__global__ void prep_kernel(const float* __restrict__ x, const int* __restrict__ qw,
                            const void* __restrict__ scales, const void* __restrict__ biases,
                            const float* __restrict__ lA, const float* __restrict__ lB,
                            const int* __restrict__ modep,
                            f16* __restrict__ Wdq, f16* __restrict__ A16,
                            f16* __restrict__ B16, f16* __restrict__ x16,
                            float* __restrict__ bias32)
{
    const int bid = blockIdx.x, tid = threadIdx.x;
    if (bid < 3840) {
        const int md = *modep;
        const int g = bid * 256 + tid;                 // group id; scale idx == g
        const float s = load_half_like(scales, g, md);
        const int4* qp = (const int4*)(qw + (size_t)g * 16);
        f16x8 w0, w1;
        #pragma unroll
        for (int v = 0; v < 4; v++) {
            const int4 q4 = qp[v];
            const int qs[4] = {q4.x, q4.y, q4.z, q4.w};
            #pragma unroll
            for (int j = 0; j < 4; j++) {
                f16 t = (f16)qs[j];
                t = t * (f16)(2.0f / 15.0f);           // f16 mul (matches ref)
                t = t - (f16)1.0f;                     // f16 sub
                const f16 w = (f16)((float)t * s);     // f32 scale mul, round once
                if (v < 2) w0[v * 4 + j] = w; else w1[(v - 2) * 4 + j] = w;
            }
        }
        *(f16x8*)(Wdq + (size_t)g * 16) = w0;
        *(f16x8*)(Wdq + (size_t)g * 16 + 8) = w1;
    } else if (bid < 4320) {
        const int i = (bid - 3840) * 1024 + tid * 4;
        const float4 a = *(const float4*)(lA + i);
        f16x4 o = {(f16)a.x, (f16)a.y, (f16)a.z, (f16)a.w};
        *(f16x4*)(A16 + i) = o;
    } else if (bid < 4800) {
        const int i = (bid - 4320) * 1024 + tid * 4;
        const float4 a = *(const float4*)(lB + i);
        f16x4 o = {(f16)(0.125f * a.x), (f16)(0.125f * a.y),
                   (f16)(0.125f * a.z), (f16)(0.125f * a.w)};
        *(f16x4*)(B16 + i) = o;
    } else if (bid < 12992) {
        const int i = (bid - 4800) * 1024 + tid * 4;
        const float4 a = *(const float4*)(x + i);
        f16x4 o = {(f16)a.x, (f16)a.y, (f16)a.z, (f16)a.w};
        *(f16x4*)(x16 + i) = o;
    } else {
        const int md = *modep;
        const int i = (bid - 12992) * 1024 + tid * 4;
        float4 o;
        o.x = load_half_like(biases, i, md);
        o.y = load_half_like(biases, i + 1, md);
        o.z = load_half_like(biases, i + 2, md);
        o.w = load_half_like(biases, i + 3, md);
        *(float4*)(bias32 + i) = o;
    }
}

// ---------------------------------------------------------------------------
// Fused QLoRA layer. ROUND 14: T14 register-staged pipeline (global->reg->LDS),
// r9 geometry (128x128, BK=64, 4 waves, 2 LDS buffers, 72KB, 2 blocks/CU).
// Evidence so far: r8-r13 obey one law -- time = DMA-staged bytes / ~6 B/cyc/CU
// -- invariant to wait discipline, buffers, occupancy, stagger, tile shape
// (r13: 1.5MB/CU -> 109us, same 6 B/cyc). m97 gets 22 B/cyc with the same
// global_load_lds instruction, so the suspect is OUR DMA request stream.
// The one untested transport: clean reg-staging with STATIC ping-pong names
// (r8's version was void -- runtime-indexed slots -> scratch). This round:
//   per K-step: 9 global_load_dwordx4 -> named set (issued distance-2 via
//   two static sets, unroll-2); after MFMAs: counted s_waitcnt vmcnt(9)
//   (never 0 mid-loop) -> 9 swizzled ds_write_b128 -> back buffer; one raw
//   s_barrier per iter. Swizzle/LDS image/read pattern/MFMA order are
//   bit-identical to r9 (swizzle now applied at ds_write instead of the
//   global source). ~204 VGPR. If dur stays ~78us, the 6 B/cyc law is
//   transport-independent and staging is exonerated -> go algorithmic.
// ---------------------------------------------------------------------------
__global__ __launch_bounds__(256, 2)
void layer_kernel(const f16* __restrict__ X16, const f16* __restrict__ W,
                  const f16* __restrict__ AL, const f16* __restrict__ BL,
                  const float* __restrict__ biasL, const float* __restrict__ resid,
                  float* __restrict__ out32, f16* __restrict__ out16, int do_relu)
{
    __shared__ __align__(16) f16 lds[36864];   // 2 x (sA 16KB | sB 16KB | sL 4KB)

    const int tid  = threadIdx.x;
    const int lane = tid & 63;
    const int wv   = tid >> 6;          // wave 0..3
    const int wy   = wv >> 1, wx = wv & 1;
    const int by   = blockIdx.x & 63;   // row block (64) -> XCD = bid%8
    const int bx   = blockIdx.x >> 6;   // col block (8)
    const int row0 = by << 7;
    const int col0 = bx << 7;

    // staging: lane -> (row lr, chunk pc); GLOBAL read linear (gk), LDS
    // write swizzled (wc) -> same LDS image as r9's source-side swizzle.
    const int lr = lane >> 3;           // row within 8-row bundle
    const int pc = lane & 7;            // 16B chunk
    const int gk = pc << 3;             // linear global col offset (elems)
    const int wc = ((pc ^ lr) << 3);    // swizzled LDS col offset (elems)

    // fragment read constants (XOR-swizzled reads; validated r0-r9)
    const int m15 = lane & 15;
    const int q2  = lane >> 4;          // 0..3
    const int sw  = m15 & 7;
    const int po0 = ((q2 ^ sw) << 3);         // s=0 physical col (elems)
    const int po1 = (((4 + q2) ^ sw) << 3);   // s=1 physical col (elems)
    const int q8  = q2 << 3;

    f32x4 acc[4][4] = {};
    f32x4 tacc[2][2] = {};

    // two STATIC staging sets (9 x f16x8 each = 36 VGPR/set)
    f16x8 ax0[4], aw0[4], al0;
    f16x8 ax1[4], aw1[4], al1;

    auto gload = [&](int kt, f16x8 (&sx)[4], f16x8 (&swr)[4], f16x8 &sl) {
        const int kb = (kt << 6) + gk;
        #pragma unroll
        for (int i = 0; i < 4; i++) {
            sx[i]  = *(const f16x8*)(X16 + (size_t)(row0 + wv * 32 + i * 8 + lr) * 1024 + kb);
            swr[i] = *(const f16x8*)(W   + (size_t)(col0 + wv * 32 + i * 8 + lr) * 1024 + kb);
        }
        sl = *(const f16x8*)(AL + (size_t)(wv * 8 + lr) * 1024 + kb);
    };
    auto swrite = [&](int bsel, f16x8 (&sx)[4], f16x8 (&swr)[4], f16x8 &sl) {
        f16* buf = lds + bsel * 18432;
        #pragma unroll
        for (int i = 0; i < 4; i++) {
            *(f16x8*)(buf + (wv * 32 + i * 8 + lr) * 64 + wc) = sx[i];
            *(f16x8*)(buf + 8192 + (wv * 32 + i * 8 + lr) * 64 + wc) = swr[i];
        }
        *(f16x8*)(buf + 16384 + (wv * 8 + lr) * 64 + wc) = sl;
    };

    // ---- prologue: sets 0,1 in flight; write set0 -> buf0 ----
    gload(0, ax0, aw0, al0);
    gload(1, ax1, aw1, al1);
    asm volatile("s_waitcnt vmcnt(9)" ::: "memory");   // set0 done, set1 flying
    __builtin_amdgcn_sched_barrier(0);
    swrite(0, ax0, aw0, al0);
    asm volatile("s_waitcnt lgkmcnt(0)" ::: "memory");
    __builtin_amdgcn_s_barrier();

    // step kt: buf[kt&1] readable; recv set <- kt+2; write set (kt+1) -> LDS
    auto step = [&](int kt, f16x8 (&rx)[4], f16x8 (&rw)[4], f16x8 &rl,
                            f16x8 (&px)[4], f16x8 (&pw)[4], f16x8 &pl) {
        const f16* cur = lds + (kt & 1) * 18432;
        const f16* sA = cur;
        const f16* sB = cur + 8192;
        const f16* sL = cur + 16384;

        #pragma unroll
        for (int s = 0; s < 2; s++) {
            const int po = s ? po1 : po0;
            f16x8 af[4], bf[4], lf[2];
            #pragma unroll
            for (int mi = 0; mi < 4; mi++)
                af[mi] = *(const f16x8*)(sA + (wy * 64 + mi * 16 + m15) * 64 + po);
            #pragma unroll
            for (int ni = 0; ni < 4; ni++)
                bf[ni] = *(const f16x8*)(sB + (wx * 64 + ni * 16 + m15) * 64 + po);
            #pragma unroll
            for (int pi = 0; pi < 2; pi++)
                lf[pi] = *(const f16x8*)(sL + (pi * 16 + m15) * 64 + po);
            if (s == 0 && kt < 14) gload(kt + 2, rx, rw, rl);  // distance-2 issue
            asm volatile("s_waitcnt lgkmcnt(0)" ::: "memory");
            __builtin_amdgcn_sched_barrier(0);   // MFMAs must not hoist (rule 18)
            #pragma unroll
            for (int mi = 0; mi < 4; mi++)
                #pragma unroll
                for (int ni = 0; ni < 4; ni++)
                    acc[mi][ni] = __builtin_amdgcn_mfma_f32_16x16x32_f16(af[mi], bf[ni], acc[mi][ni], 0, 0, 0);
            #pragma unroll
            for (int mi = 0; mi < 2; mi++)
                #pragma unroll
                for (int pi = 0; pi < 2; pi++)
                    tacc[mi][pi] = __builtin_amdgcn_mfma_f32_16x16x32_f16(af[s ? 2 : 2 * wx + mi - mi, 0] /*placeholder*/, lf[pi], tacc[mi][pi], 0, 0, 0);
        }
    };
    (void)step; // placeholder guard -- real loop below

    // NOTE: lambda above replaced by explicit loop to keep tacc indexing
    // identical to r9 (af[2*wx+mi]); see body below.
    {
        #pragma unroll 1
        for (int k2 = 0; k2 < 8; k2++) {
            #pragma unroll
            for (int half = 0; half < 2; half++) {
                const int kt = 2 * k2 + half;
                const f16* cur = lds + (kt & 1) * 18432;
                const f16* sA = cur;
                const f16* sB = cur + 8192;
                const f16* sL = cur + 16384;

                #pragma unroll
                for (int s = 0; s < 2; s++) {
                    const int po = s ? po1 : po0;
                    f16x8 af[4], bf[4], lf[2];
                    #pragma unroll
                    for (int mi = 0; mi < 4; mi++)
                        af[mi] = *(const f16x8*)(sA + (wy * 64 + mi * 16 + m15) * 64 + po);
                    #pragma unroll
                    for (int ni = 0; ni < 4; ni++)
                        bf[ni] = *(const f16x8*)(sB + (wx * 64 + ni * 16 + m15) * 64 + po);
                    #pragma unroll
                    for (int pi = 0; pi < 2; pi++)
                        lf[pi] = *(const f16x8*)(sL + (pi * 16 + m15) * 64 + po);
                    if (s == 0 && kt < 14) {
                        if (half == 0) gload(kt + 2, ax0, aw0, al0);
                        else           gload(kt + 2, ax1, aw1, al1);
                    }
                    asm volatile("s_waitcnt lgkmcnt(0)" ::: "memory");
                    __builtin_amdgcn_sched_barrier(0);
                    #pragma unroll
                    for (int mi = 0; mi < 4; mi++)
                        #pragma unroll
                        for (int ni = 0; ni < 4; ni++)
                            acc[mi][ni] = __builtin_amdgcn_mfma_f32_16x16x32_f16(af[mi], bf[ni], acc[mi][ni], 0, 0, 0);
                    #pragma unroll
                    for (int mi = 0; mi < 2; mi++)
                        #pragma unroll
                        for (int pi = 0; pi < 2; pi++)
                            tacc[mi][pi] = __builtin_amdgcn_mfma_f32_16x16x32_f16(af[2 * wx + mi], lf[pi], tacc[mi][pi], 0, 0, 0);
                }

                if (kt < 15) {
                    if (kt < 14) asm volatile("s_waitcnt vmcnt(9)" ::: "memory");
                    else         asm volatile("s_waitcnt vmcnt(0)" ::: "memory");
                    __builtin_amdgcn_sched_barrier(0);
                    if (half == 0) swrite((kt + 1) & 1, ax1, aw1, al1);
                    else           swrite((kt + 1) & 1, ax0, aw0, al0);
                    asm volatile("s_waitcnt lgkmcnt(0)" ::: "memory");
                    __builtin_amdgcn_s_barrier();
                }
            }
        }
    }

    // ---- epilogue: lora stage-2 ----
    __syncthreads();
    float* Tl = (float*)lds;   // [128][33] f32 padded, aliases buffer 0
    const int q4 = (lane >> 4) << 2;
    {
        #pragma unroll
        for (int mi = 0; mi < 2; mi++)
            #pragma unroll
            for (int pi = 0; pi < 2; pi++)
                #pragma unroll
                for (int r = 0; r < 4; r++)
                    Tl[(wy * 64 + wx * 32 + mi * 16 + q4 + r) * 33 + pi * 16 + m15] = tacc[mi][pi][r];
    }
    __syncthreads();

    f16x8 tf[4];    // T in A-fragment layout (k = lora dim, K=32 -> one k-step)
    #pragma unroll
    for (int mi = 0; mi < 4; mi++) {
        const float* tp = Tl + (wy * 64 + mi * 16 + m15) * 33 + q8;
        f16x8 v;
        #pragma unroll
        for (int j = 0; j < 8; j++) v[j] = (f16)tp[j];
        tf[mi] = v;
    }
    f16x8 bfr[4]; float bb[4];
    #pragma unroll
    for (int ni = 0; ni < 4; ni++) {
        const int colg = col0 + wx * 64 + ni * 16 + m15;
        bfr[ni] = *(const f16x8*)(BL + (size_t)colg * 32 + q8);  // pre-scaled 0.125
        bb[ni] = biasL[colg];
    }
    #pragma unroll
    for (int mi = 0; mi < 4; mi++)
        #pragma unroll
        for (int ni = 0; ni < 4; ni++) {
            #pragma unroll
            for (int r = 0; r < 4; r++)
                acc[mi][ni][r] += bb[ni];      // f32 bias add (ref promotes to f32)
            acc[mi][ni] = __builtin_amdgcn_mfma_f32_16x16x32_f16(tf[mi], bfr[ni], acc[mi][ni], 0, 0, 0);
        }

    // ---- epilogue: coalesced store through LDS ----
    __syncthreads();   // all waves done with Tl before LDS reuse
    if (out16) {
        // f16 path (j=0/1): relu, pack to LDS [128][136], store 16B/lane
        f16* ot = lds;
        #pragma unroll
        for (int mi = 0; mi < 4; mi++)
            #pragma unroll
            for (int ni = 0; ni < 4; ni++)
                #pragma unroll
                for (int r = 0; r < 4; r++) {
                    float v = acc[mi][ni][r];
                    if (do_relu) v = fmaxf(v, 0.0f);
                    ot[(wy * 64 + mi * 16 + q4 + r) * 136 + wx * 64 + ni * 16 + m15] = (f16)v;
                }
        __syncthreads();
        const int rr = tid >> 4;            // 0..15
        const int cc = (tid & 15) << 3;     // 16B chunks
        #pragma unroll
        for (int it = 0; it < 8; it++) {
            const int r = it * 16 + rr;
            const f16x8 v = *(const f16x8*)(ot + r * 136 + cc);
            *(f16x8*)(out16 + (size_t)(row0 + r) * 1024 + col0 + cc) = v;
        }
    } else {
        // f32 path (j=2): two 64-row halves through LDS [64][140],
        // coalesced resid read + coalesced f32 store.
        float* otf = (float*)lds;
        const int rr = tid >> 5;            // 0..7
        const int cc = (tid & 31) << 2;     // 16B chunks (f32)
        #pragma unroll
        for (int half = 0; half < 2; half++) {
            if (wy == half) {
                #pragma unroll
                for (int mi = 0; mi < 4; mi++)
                    #pragma unroll
                    for (int ni = 0; ni < 4; ni++)
                        #pragma unroll
                        for (int r = 0; r < 4; r++)
                            otf[(mi * 16 + q4 + r) * 140 + wx * 64 + ni * 16 + m15] = acc[mi][ni][r];
            }
            __syncthreads();
            #pragma unroll
            for (int it = 0; it < 8; it++) {
                const int r = it * 8 + rr;
                f32x4 v = *(const f32x4*)(otf + r * 140 + cc);
                const size_t gidx = (size_t)(row0 + half * 64 + r) * 1024 + col0 + cc;
                const f32x4 rs = *(const f32x4*)(resid + gidx);
                v += rs;
                *(f32x4*)(out32 + gidx) = v;
            }
            if (half == 0) __syncthreads();
        }
    }
}

// ---------------------------------------------------------------------------
// LayerNorm over rows of h (f32, in place) + f16 copy for next GEMM input.
// ---------------------------------------------------------------------------
__global__ void ln_kernel(float* __restrict__ h, f16* __restrict__ h16,
                          const float* __restrict__ g, const float* __restrict__ b)
{
    const int row = blockIdx.x, tid = threadIdx.x;
    float* hp = h + (size_t)row * 1024;
    const int c = tid * 4;
    const float4 v = *(const float4*)(hp + c);
    float s = v.x + v.y + v.z + v.w;
    #pragma unroll
    for (int off = 32; off > 0; off >>= 1) s += __shfl_down(s, off);
    __shared__ float r1[4], r2[4];
    const int wv = tid >> 6, lane = tid & 63;
    if (lane == 0) r1[wv] = s;
    __syncthreads();
    const float mu = (r1[0] + r1[1] + r1[2] + r1[3]) * (1.0f / 1024.0f);
    const float dx = v.x - mu, dy = v.y - mu, dz = v.z - mu, dw = v.w - mu;
    float s2 = dx * dx + dy * dy + dz * dz + dw * dw;
    #pragma unroll
    for (int off = 32; off > 0; off >>= 1) s2 += __shfl_down(s2, off);
    if (lane == 0) r2[wv] = s2;
    __syncthreads();
    const float var = (r2[0] + r2[1] + r2[2] + r2[3]) * (1.0f / 1024.0f);
    const float rs = 1.0f / sqrtf(var + 1e-5f);
    float4 o;
    o.x = dx * rs * g[c]     + b[c];
    o.y = dy * rs * g[c + 1] + b[c + 1];
    o.z = dz * rs * g[c + 2] + b[c + 2];
    o.w = dw * rs * g[c + 3] + b[c + 3];
    *(float4*)(hp + c) = o;
    f16x4 o16 = {(f16)o.x, (f16)o.y, (f16)o.z, (f16)o.w};
    *(f16x4*)(h16 + (size_t)row * 1024 + c) = o16;
}

// ---------------------------------------------------------------------------
// ws layout (~64 MB): mode@0 | bias32@64 | Wdq@65536 | A16 | B16 | fA | fB
// f32 residual carrier lives in d_out (overwritten fully every call).
// ---------------------------------------------------------------------------
extern "C" void kernel_launch(void* const* d_in, const int* in_sizes, int n_in,
                              void* d_out, int out_size, void* d_ws, size_t ws_size,
                              hipStream_t stream)
{
    const float* x      = (const float*)d_in[0];
    const int*   qw     = (const int*)d_in[1];
    const void*  scales = d_in[2];
    const void*  biases = d_in[3];
    const float* lA     = (const float*)d_in[4];
    const float* lB     = (const float*)d_in[5];
    const float* lng    = (const float*)d_in[6];
    const float* lnb    = (const float*)d_in[7];
    float* out = (float*)d_out;

    char* ws = (char*)d_ws;
    int*   mode   = (int*)(ws);
    float* bias32 = (float*)(ws + 64);
    f16* Wdq = (f16*)(ws + 65536u);
    f16* A16 = (f16*)(ws + 31522816u);
    f16* B16 = (f16*)(ws + 32505856u);
    f16* fA  = (f16*)(ws + 33488896u);
    f16* fB  = (f16*)(ws + 50266112u);
    float* h32 = out;   // residual carrier in d_out

    detect_kernel<<<1, 64, 0, stream>>>((const unsigned short*)scales, mode);
    prep_kernel<<<13007, 256, 0, stream>>>(x, qw, scales, biases, lA, lB, mode,
                                           Wdq, A16, B16, fA, bias32);

    int li = 0;
    for (int blk = 0; blk < 6; blk++) {
        const float* resid = (blk == 0) ? x : h32;
        for (int j = 0; j < 3; j++, li++) {
            const int wl = li < 15 ? li : 14;      // JAX clamps q_w[15..17] -> 14
            const f16* in16 = (j == 1) ? fB : fA;
            f16* o16 = (j == 0) ? fB : (j == 1 ? fA : (f16*)nullptr);
            float* o32 = nullptr;
            const float* rz = nullptr;
            if (j == 2) { o32 = h32; rz = resid; }
            layer_kernel<<<512, 256, 0, stream>>>(in16,
                Wdq + (size_t)wl * 1048576,
                A16 + (size_t)wl * 32768,
                B16 + (size_t)wl * 32768,
                bias32 + (size_t)wl * 1024,
                rz, o32, o16, j < 2 ? 1 : 0);
        }
        if (blk < 5)
            ln_kernel<<<8192, 256, 0, stream>>>(h32, fA, lng + blk * 1024, lnb + blk * 1024);
    }
}

// Round 8
// 1383.473 us; speedup vs baseline: 3.6355x; 1.0472x over previous
//
#include <hip/hip_runtime.h>

typedef _Float16 f16;
typedef _Float16 f16x8 __attribute__((ext_vector_type(8)));
typedef _Float16 f16x4 __attribute__((ext_vector_type(4)));
typedef float f32x4 __attribute__((ext_vector_type(4)));

// ---------------------------------------------------------------------------
// ROUND 16: K-tiled operand layouts -> every staging instruction reads 1KB
// CONTIGUOUS global memory.
// The ~150cyc/VMEM-instr law (r9-r14) survived changes of transport, waits,
// occupancy, and traffic -- but every round shared one invariant: each
// staging instruction's 64 lanes straddle 8-16 rows at 2KB stride (row-major
// [.][1024] f16). 16 cache lines at 2KB granularity can collapse onto 1-2 L2
// slices (slice hash on low addr bits) -> request serializes ~150cyc. m97
// (22 B/cyc, same instruction) streams different stride bits. Fix: tiled
// layouts X_t[kt][8192][64], W_t[li][kt][1024][64], A_t[li][kt][32][64] --
// an 8-row tile slice is one contiguous 1KB burst (16 CONSECUTIVE lines).
// Source-side XOR swizzle now permutes 16B chunks WITHIN the same 1KB ->
// LDS image bit-identical to r9; fragment reads / MFMA order / epilogue
// unchanged -> bit-identical output. Producers write tiled: prep (x, W,
// lora-A), layer f16 epilogue, LN f16 copy -- all still 8-16B/lane coalesced.
// Skeleton = r9 exactly (128x128, BK=64, 4 waves, 72KB dbuf, grid 512).
// ---------------------------------------------------------------------------

// ---------------------------------------------------------------------------
// Dtype probe: scales true values lie in [0.01, 0.06]. Writes mode:
// 0=f16, 1=bf16, 2=f32. Graph-safe (no host sync).
// ---------------------------------------------------------------------------
__global__ void detect_kernel(const unsigned short* __restrict__ sc, int* __restrict__ mode)
{
    if (threadIdx.x != 0 || blockIdx.x != 0) return;
    bool ok16 = true, okbf = true;
    for (int i = 0; i < 64; i++) {
        const unsigned short b = sc[i];
        union { unsigned short u; f16 h; } ch; ch.u = b;
        const float fv = (float)ch.h;
        if (!(fv > 0.008f && fv < 0.062f)) ok16 = false;
        union { unsigned int u; float f; } cb; cb.u = ((unsigned int)b) << 16;
        if (!(cb.f > 0.008f && cb.f < 0.062f)) okbf = false;
    }
    *mode = ok16 ? 0 : (okbf ? 1 : 2);
}

__device__ __forceinline__ float load_half_like(const void* p, int i, int mode)
{
    if (mode == 0) return (float)((const f16*)p)[i];
    if (mode == 1) {
        union { unsigned int u; float f; } c;
        c.u = ((unsigned int)((const unsigned short*)p)[i]) << 16;
        return c.f;
    }
    return ((const float*)p)[i];
}

// ---------------------------------------------------------------------------
// Prep: dequant 4-bit -> f16 weights (f16 code math, f32 scale mul, round
// once -- matches ref), lora_A -> f16, lora_B*0.125 -> f16, x -> f16,
// biases -> f32. ALL f16 operand outputs in K-TILED layout:
//   W_t:  li*1048576 + kt*65536  + col*64 + kc   (kt = k>>6, kc = k&63)
//   A_t:  li*32768   + kt*2048   + p*64   + kc
//   x_t:            kt*524288    + row*64 + kc
// ---------------------------------------------------------------------------
__global__ void prep_kernel(const float* __restrict__ x, const int* __restrict__ qw,
                            const void* __restrict__ scales, const void* __restrict__ biases,
                            const float* __restrict__ lA, const float* __restrict__ lB,
                            const int* __restrict__ modep,
                            f16* __restrict__ Wdq, f16* __restrict__ A16,
                            f16* __restrict__ B16, f16* __restrict__ x16,
                            float* __restrict__ bias32)
{
    const int bid = blockIdx.x, tid = threadIdx.x;
    if (bid < 3840) {
        const int md = *modep;
        const int g = bid * 256 + tid;                 // group id; scale idx == g
        const float s = load_half_like(scales, g, md);
        const int4* qp = (const int4*)(qw + (size_t)g * 16);
        f16x8 w0, w1;
        #pragma unroll
        for (int v = 0; v < 4; v++) {
            const int4 q4 = qp[v];
            const int qs[4] = {q4.x, q4.y, q4.z, q4.w};
            #pragma unroll
            for (int j = 0; j < 4; j++) {
                f16 t = (f16)qs[j];
                t = t * (f16)(2.0f / 15.0f);           // f16 mul (matches ref)
                t = t - (f16)1.0f;                     // f16 sub
                const f16 w = (f16)((float)t * s);     // f32 scale mul, round once
                if (v < 2) w0[v * 4 + j] = w; else w1[(v - 2) * 4 + j] = w;
            }
        }
        // tiled dest: row = g>>6 (li*1024+col), grp = g&63 -> k0 = grp*16
        const int row = g >> 6;
        const int li  = row >> 10;
        const int col = row & 1023;
        const int grp = g & 63;
        const size_t dst = (size_t)li * 1048576 + (size_t)(grp >> 2) * 65536
                         + (size_t)col * 64 + ((grp & 3) << 4);
        *(f16x8*)(Wdq + dst) = w0;
        *(f16x8*)(Wdq + dst + 8) = w1;
    } else if (bid < 4320) {
        const int i = (bid - 3840) * 1024 + tid * 4;   // li*32768 + p*1024 + k
        const float4 a = *(const float4*)(lA + i);
        f16x4 o = {(f16)a.x, (f16)a.y, (f16)a.z, (f16)a.w};
        const int li = i >> 15, j = i & 32767;
        const int p = j >> 10, k = j & 1023;
        *(f16x4*)(A16 + (size_t)li * 32768 + (size_t)(k >> 6) * 2048
                      + (size_t)p * 64 + (k & 63)) = o;
    } else if (bid < 4800) {
        const int i = (bid - 4320) * 1024 + tid * 4;
        const float4 a = *(const float4*)(lB + i);
        f16x4 o = {(f16)(0.125f * a.x), (f16)(0.125f * a.y),
                   (f16)(0.125f * a.z), (f16)(0.125f * a.w)};
        *(f16x4*)(B16 + i) = o;                        // [col][32] layout kept
    } else if (bid < 12992) {
        const int row = bid - 4800;                    // one row per block
        const int k = tid * 4;
        const float4 a = *(const float4*)(x + (size_t)row * 1024 + k);
        f16x4 o = {(f16)a.x, (f16)a.y, (f16)a.z, (f16)a.w};
        *(f16x4*)(x16 + (size_t)(k >> 6) * 524288 + (size_t)row * 64 + (k & 63)) = o;
    } else {
        const int md = *modep;
        const int i = (bid - 12992) * 1024 + tid * 4;
        float4 o;
        o.x = load_half_like(biases, i, md);
        o.y = load_half_like(biases, i + 1, md);
        o.z = load_half_like(biases, i + 2, md);
        o.w = load_half_like(biases, i + 3, md);
        *(float4*)(bias32 + i) = o;
    }
}

// global -> LDS direct DMA, 16B per lane (dest: wave-uniform base + lane*16B)
__device__ __forceinline__ void gl_lds16(const f16* g, f16* l)
{
    __builtin_amdgcn_global_load_lds(
        (const __attribute__((address_space(1))) void*)g,
        (__attribute__((address_space(3))) void*)l, 16, 0, 0);
}

// ---------------------------------------------------------------------------
// Fused QLoRA layer. r9 skeleton: 128x128 tile, BK=64, 4 waves, 2-phase
// barrier pipeline, 72KB LDS dbuf, grid 512 (2 blocks/CU). Only the GLOBAL
// source addressing changed: tiled layouts make each gl_lds16 a contiguous
// 1KB burst. LDS image / fragment reads / MFMA order are r9-bit-identical.
// ---------------------------------------------------------------------------
__global__ __launch_bounds__(256, 2)
void layer_kernel(const f16* __restrict__ X16, const f16* __restrict__ W,
                  const f16* __restrict__ AL, const f16* __restrict__ BL,
                  const float* __restrict__ biasL, const float* __restrict__ resid,
                  float* __restrict__ out32, f16* __restrict__ out16, int do_relu)
{
    __shared__ __align__(16) f16 lds[36864];   // 2 x (sA 16KB | sB 16KB | sL 4KB)

    const int tid  = threadIdx.x;
    const int lane = tid & 63;
    const int wv   = tid >> 6;          // wave 0..3
    const int wy   = wv >> 1, wx = wv & 1;
    const int by   = blockIdx.x & 63;   // row block (64) -> XCD = bid%8
    const int bx   = blockIdx.x >> 6;   // col block (8)
    const int row0 = by << 7;
    const int col0 = bx << 7;

    // staging: lane -> (row lr, chunk pc); LDS dest LINEAR (lane*16B).
    // swizzle on source chunk (pc^lr) -- now WITHIN one contiguous 1KB run.
    const int lr = lane >> 3;           // row-slice within 8-row bundle
    const int pc = lane & 7;            // LDS 16B chunk this lane lands in
    const int csw = ((pc ^ lr) << 3);   // swizzled chunk offset (elems)

    // fragment read constants (XOR-swizzled reads; validated r0-r14)
    const int m15 = lane & 15;
    const int q2  = lane >> 4;          // 0..3
    const int sw  = m15 & 7;
    const int po0 = ((q2 ^ sw) << 3);         // s=0 physical col (elems)
    const int po1 = (((4 + q2) ^ sw) << 3);   // s=1 physical col (elems)
    const int q8  = q2 << 3;

    f32x4 acc[4][4] = {};
    f32x4 tacc[2][2] = {};

    // tiled sources: X_t[kt][8192][64], W_t[kt][1024][64], A_t[kt][32][64]
    auto stage = [&](f16* buf, int kt) {
        const f16* Xt = X16 + (size_t)kt * 524288 + csw;
        const f16* Wt = W   + (size_t)kt * 65536  + csw;
        const f16* At = AL  + (size_t)kt * 2048   + csw;
        #pragma unroll
        for (int i = 0; i < 4; i++) {
            gl_lds16(Xt + (size_t)(row0 + wv * 32 + i * 8 + lr) * 64,
                     buf + (wv * 32 + i * 8) * 64);
            gl_lds16(Wt + (size_t)(col0 + wv * 32 + i * 8 + lr) * 64,
                     buf + 8192 + (wv * 32 + i * 8) * 64);
        }
        gl_lds16(At + (size_t)(wv * 8 + lr) * 64,
                 buf + 16384 + wv * 8 * 64);
    };

    stage(lds, 0);                       // prologue: tile 0 in flight

    for (int kt = 0; kt < 16; kt++) {
        __syncthreads();                 // drains vmcnt(0): buf[kt&1] staged
        const f16* cur = lds + (kt & 1) * 18432;
        const f16* sA = cur;
        const f16* sB = cur + 8192;
        const f16* sL = cur + 16384;

        // issue next tile's DMA immediately (r9 2-phase structure)
        if (kt < 15) stage(lds + ((kt + 1) & 1) * 18432, kt + 1);

        // read ALL fragments for this tile (swizzled, conflict-free)
        f16x8 af[2][4], bf[2][4], lf[2][2];
        #pragma unroll
        for (int s = 0; s < 2; s++) {
            const int po = s ? po1 : po0;
            #pragma unroll
            for (int mi = 0; mi < 4; mi++)
                af[s][mi] = *(const f16x8*)(sA + (wy * 64 + mi * 16 + m15) * 64 + po);
            #pragma unroll
            for (int ni = 0; ni < 4; ni++)
                bf[s][ni] = *(const f16x8*)(sB + (wx * 64 + ni * 16 + m15) * 64 + po);
            #pragma unroll
            for (int pi = 0; pi < 2; pi++)
                lf[s][pi] = *(const f16x8*)(sL + (pi * 16 + m15) * 64 + po);
        }

        // compute (48 MFMAs); next-tile DMA flies underneath
        #pragma unroll
        for (int s = 0; s < 2; s++) {
            #pragma unroll
            for (int mi = 0; mi < 4; mi++)
                #pragma unroll
                for (int ni = 0; ni < 4; ni++)
                    acc[mi][ni] = __builtin_amdgcn_mfma_f32_16x16x32_f16(af[s][mi], bf[s][ni], acc[mi][ni], 0, 0, 0);
            // lora stage-1: each wave covers its own 32 rows (m-frags 2wx, 2wx+1)
            #pragma unroll
            for (int mi = 0; mi < 2; mi++)
                #pragma unroll
                for (int pi = 0; pi < 2; pi++)
                    tacc[mi][pi] = __builtin_amdgcn_mfma_f32_16x16x32_f16(af[s][2 * wx + mi], lf[s][pi], tacc[mi][pi], 0, 0, 0);
        }
    }

    // ---- epilogue: lora stage-2 ----
    __syncthreads();
    float* Tl = (float*)lds;   // [128][33] f32 padded, aliases buffer 0
    const int q4 = (lane >> 4) << 2;
    {
        #pragma unroll
        for (int mi = 0; mi < 2; mi++)
            #pragma unroll
            for (int pi = 0; pi < 2; pi++)
                #pragma unroll
                for (int r = 0; r < 4; r++)
                    Tl[(wy * 64 + wx * 32 + mi * 16 + q4 + r) * 33 + pi * 16 + m15] = tacc[mi][pi][r];
    }
    __syncthreads();

    f16x8 tf[4];    // T in A-fragment layout (k = lora dim, K=32 -> one k-step)
    #pragma unroll
    for (int mi = 0; mi < 4; mi++) {
        const float* tp = Tl + (wy * 64 + mi * 16 + m15) * 33 + q8;
        f16x8 v;
        #pragma unroll
        for (int j = 0; j < 8; j++) v[j] = (f16)tp[j];
        tf[mi] = v;
    }
    f16x8 bfr[4]; float bb[4];
    #pragma unroll
    for (int ni = 0; ni < 4; ni++) {
        const int colg = col0 + wx * 64 + ni * 16 + m15;
        bfr[ni] = *(const f16x8*)(BL + (size_t)colg * 32 + q8);  // pre-scaled 0.125
        bb[ni] = biasL[colg];
    }
    #pragma unroll
    for (int mi = 0; mi < 4; mi++)
        #pragma unroll
        for (int ni = 0; ni < 4; ni++) {
            #pragma unroll
            for (int r = 0; r < 4; r++)
                acc[mi][ni][r] += bb[ni];      // f32 bias add (ref promotes to f32)
            acc[mi][ni] = __builtin_amdgcn_mfma_f32_16x16x32_f16(tf[mi], bfr[ni], acc[mi][ni], 0, 0, 0);
        }

    // ---- epilogue: coalesced store through LDS ----
    __syncthreads();   // all waves done with Tl before LDS reuse
    if (out16) {
        // f16 path (j=0/1): relu, pack to LDS [128][136], store 16B/lane to
        // the TILED next-layer input: dest = (col>>6)*524288 + row*64 + col&63
        f16* ot = lds;
        #pragma unroll
        for (int mi = 0; mi < 4; mi++)
            #pragma unroll
            for (int ni = 0; ni < 4; ni++)
                #pragma unroll
                for (int r = 0; r < 4; r++) {
                    float v = acc[mi][ni][r];
                    if (do_relu) v = fmaxf(v, 0.0f);
                    ot[(wy * 64 + mi * 16 + q4 + r) * 136 + wx * 64 + ni * 16 + m15] = (f16)v;
                }
        __syncthreads();
        const int rr = tid >> 4;            // 0..15
        const int cc = (tid & 15) << 3;     // 16B chunks (0..120)
        f16* o0 = out16 + (size_t)(2 * bx + (cc >> 6)) * 524288 + (cc & 63);
        #pragma unroll
        for (int it = 0; it < 8; it++) {
            const int r = it * 16 + rr;
            const f16x8 v = *(const f16x8*)(ot + r * 136 + cc);
            *(f16x8*)(o0 + (size_t)(row0 + r) * 64) = v;
        }
    } else {
        // f32 path (j=2): two 64-row halves through LDS [64][140],
        // coalesced resid read + coalesced f32 store (h32 stays LINEAR).
        float* otf = (float*)lds;
        const int rr = tid >> 5;            // 0..7
        const int cc = (tid & 31) << 2;     // 16B chunks (f32)
        #pragma unroll
        for (int half = 0; half < 2; half++) {
            if (wy == half) {
                #pragma unroll
                for (int mi = 0; mi < 4; mi++)
                    #pragma unroll
                    for (int ni = 0; ni < 4; ni++)
                        #pragma unroll
                        for (int r = 0; r < 4; r++)
                            otf[(mi * 16 + q4 + r) * 140 + wx * 64 + ni * 16 + m15] = acc[mi][ni][r];
            }
            __syncthreads();
            #pragma unroll
            for (int it = 0; it < 8; it++) {
                const int r = it * 8 + rr;
                f32x4 v = *(const f32x4*)(otf + r * 140 + cc);
                const size_t gidx = (size_t)(row0 + half * 64 + r) * 1024 + col0 + cc;
                const f32x4 rs = *(const f32x4*)(resid + gidx);
                v += rs;
                *(f32x4*)(out32 + gidx) = v;
            }
            if (half == 0) __syncthreads();
        }
    }
}

// ---------------------------------------------------------------------------
// LayerNorm over rows of h (f32 linear, in place) + f16 copy in TILED layout
// for the next GEMM input.
// ---------------------------------------------------------------------------
__global__ void ln_kernel(float* __restrict__ h, f16* __restrict__ h16,
                          const float* __restrict__ g, const float* __restrict__ b)
{
    const int row = blockIdx.x, tid = threadIdx.x;
    float* hp = h + (size_t)row * 1024;
    const int c = tid * 4;
    const float4 v = *(const float4*)(hp + c);
    float s = v.x + v.y + v.z + v.w;
    #pragma unroll
    for (int off = 32; off > 0; off >>= 1) s += __shfl_down(s, off);
    __shared__ float r1[4], r2[4];
    const int wv = tid >> 6, lane = tid & 63;
    if (lane == 0) r1[wv] = s;
    __syncthreads();
    const float mu = (r1[0] + r1[1] + r1[2] + r1[3]) * (1.0f / 1024.0f);
    const float dx = v.x - mu, dy = v.y - mu, dz = v.z - mu, dw = v.w - mu;
    float s2 = dx * dx + dy * dy + dz * dz + dw * dw;
    #pragma unroll
    for (int off = 32; off > 0; off >>= 1) s2 += __shfl_down(s2, off);
    if (lane == 0) r2[wv] = s2;
    __syncthreads();
    const float var = (r2[0] + r2[1] + r2[2] + r2[3]) * (1.0f / 1024.0f);
    const float rs = 1.0f / sqrtf(var + 1e-5f);
    float4 o;
    o.x = dx * rs * g[c]     + b[c];
    o.y = dy * rs * g[c + 1] + b[c + 1];
    o.z = dz * rs * g[c + 2] + b[c + 2];
    o.w = dw * rs * g[c + 3] + b[c + 3];
    *(float4*)(hp + c) = o;
    f16x4 o16 = {(f16)o.x, (f16)o.y, (f16)o.z, (f16)o.w};
    *(f16x4*)(h16 + (size_t)(c >> 6) * 524288 + (size_t)row * 64 + (c & 63)) = o16;
}

// ---------------------------------------------------------------------------
// ws layout (~64 MB): mode@0 | bias32@64 | Wdq@65536 | A16 | B16 | fA | fB
// f32 residual carrier lives in d_out (overwritten fully every call).
// ---------------------------------------------------------------------------
extern "C" void kernel_launch(void* const* d_in, const int* in_sizes, int n_in,
                              void* d_out, int out_size, void* d_ws, size_t ws_size,
                              hipStream_t stream)
{
    const float* x      = (const float*)d_in[0];
    const int*   qw     = (const int*)d_in[1];
    const void*  scales = d_in[2];
    const void*  biases = d_in[3];
    const float* lA     = (const float*)d_in[4];
    const float* lB     = (const float*)d_in[5];
    const float* lng    = (const float*)d_in[6];
    const float* lnb    = (const float*)d_in[7];
    float* out = (float*)d_out;

    char* ws = (char*)d_ws;
    int*   mode   = (int*)(ws);
    float* bias32 = (float*)(ws + 64);
    f16* Wdq = (f16*)(ws + 65536u);
    f16* A16 = (f16*)(ws + 31522816u);
    f16* B16 = (f16*)(ws + 32505856u);
    f16* fA  = (f16*)(ws + 33488896u);
    f16* fB  = (f16*)(ws + 50266112u);
    float* h32 = out;   // residual carrier in d_out

    detect_kernel<<<1, 64, 0, stream>>>((const unsigned short*)scales, mode);
    prep_kernel<<<13007, 256, 0, stream>>>(x, qw, scales, biases, lA, lB, mode,
                                           Wdq, A16, B16, fA, bias32);

    int li = 0;
    for (int blk = 0; blk < 6; blk++) {
        const float* resid = (blk == 0) ? x : h32;
        for (int j = 0; j < 3; j++, li++) {
            const int wl = li < 15 ? li : 14;      // JAX clamps q_w[15..17] -> 14
            const f16* in16 = (j == 1) ? fB : fA;
            f16* o16 = (j == 0) ? fB : (j == 1 ? fA : (f16*)nullptr);
            float* o32 = nullptr;
            const float* rz = nullptr;
            if (j == 2) { o32 = h32; rz = resid; }
            layer_kernel<<<512, 256, 0, stream>>>(in16,
                Wdq + (size_t)wl * 1048576,
                A16 + (size_t)wl * 32768,
                B16 + (size_t)wl * 32768,
                bias32 + (size_t)wl * 1024,
                rz, o32, o16, j < 2 ? 1 : 0);
        }
        if (blk < 5)
            ln_kernel<<<8192, 256, 0, stream>>>(h32, fA, lng + blk * 1024, lnb + blk * 1024);
    }
}